// Round 3
// baseline (315.500 us; speedup 1.0000x reference)
//
#include <hip/hip_runtime.h>
#include <hip/hip_bf16.h>
#include <math.h>
#include <stdint.h>

#define Bd 2
#define Nd 1024
#define Dd 1024
#define Hh 16
#define EPSf 1e-6f
#define NPB 8

typedef short s8v __attribute__((ext_vector_type(8)));
typedef float f16v __attribute__((ext_vector_type(16)));
typedef float f4v __attribute__((ext_vector_type(4)));

#define MFMA32x32(A,B,C) __builtin_amdgcn_mfma_f32_32x32x16_bf16(A,B,C,0,0,0)
#define MFMA16x16(A,B,C) __builtin_amdgcn_mfma_f32_16x16x32_bf16(A,B,C,0,0,0)

__device__ __forceinline__ void gl_lds16(const void* g, void* l) {
    __builtin_amdgcn_global_load_lds((const __attribute__((address_space(1))) unsigned int*)g,
                                     (__attribute__((address_space(3))) unsigned int*)l, 16, 0, 0);
}

__device__ __forceinline__ unsigned short bf16bits(float v) {
    __hip_bfloat16 h = __float2bfloat16(v);
    return *(unsigned short*)&h;
}
__device__ __forceinline__ float bf16rt(float v) {   // round-trip through bf16
    __hip_bfloat16 h = __float2bfloat16(v);
    return __bfloat162float(h);
}

// ---------------- Kernel 1: witness projections -> combined bf16 witness rows ----------------
// wit[row][320] bf16: [0:64)=wE, [64:128)=wS(normalized), [128:192)=wHb, [192:320)=z
// sq[row][4] f32: {|wE|^2, |wHb|^2, 1-clip(|wHb|^2), |z|^2}  (all from bf16-rounded values)
// xb: bf16 copy of x
__global__ void witness_kernel(const float* __restrict__ x,
    const float* __restrict__ WE, const float* __restrict__ bE,
    const float* __restrict__ WS, const float* __restrict__ bS,
    const float* __restrict__ WH, const float* __restrict__ bH,
    const float* __restrict__ Wrff, const float* __restrict__ brff,
    unsigned short* __restrict__ wit, float* __restrict__ sqo,
    unsigned short* __restrict__ xb)
{
    const int e = threadIdx.x;           // 0..63
    int idx = blockIdx.x;
    const int NC = Nd / NPB;             // 128
    int nc = idx % NC;
    int h = (idx / NC) % Hh;
    int b = idx / (NC * Hh);
    int n0 = nc * NPB;

    __shared__ float xs[NPB][64];
    #pragma unroll
    for (int r = 0; r < NPB; r++) {
        float xv = x[((size_t)b * Nd + n0 + r) * Dd + h * 64 + e];
        xs[r][e] = xv;
        xb[((size_t)b * Nd + n0 + r) * Dd + h * 64 + e] = bf16bits(xv);
    }
    __syncthreads();

    size_t rowbase = ((size_t)(b * Hh + h) * Nd + n0);

    // ---- Euclidean ----
    {
        float acc[NPB];
        #pragma unroll
        for (int r = 0; r < NPB; r++) acc[r] = 0.f;
        const float* Wp = WE + (size_t)h * 64 * 64 + e;
        for (int d = 0; d < 64; d++) {
            float w = Wp[(size_t)d * 64];
            #pragma unroll
            for (int r = 0; r < NPB; r++) acc[r] = fmaf(xs[r][d], w, acc[r]);
        }
        float bb = bE[h * 64 + e];
        #pragma unroll
        for (int r = 0; r < NPB; r++) {
            float v = acc[r] + bb;
            float vf = bf16rt(v);
            wit[(rowbase + r) * 320 + e] = bf16bits(v);
            float s = vf * vf;
            for (int o = 32; o > 0; o >>= 1) s += __shfl_xor(s, o, 64);
            if (e == 0) sqo[(rowbase + r) * 4 + 0] = s;
        }
    }
    // ---- Spherical ----
    {
        float acc[NPB];
        #pragma unroll
        for (int r = 0; r < NPB; r++) acc[r] = 0.f;
        const float* Wp = WS + (size_t)h * 64 * 64 + e;
        for (int d = 0; d < 64; d++) {
            float w = Wp[(size_t)d * 64];
            #pragma unroll
            for (int r = 0; r < NPB; r++) acc[r] = fmaf(xs[r][d], w, acc[r]);
        }
        float bb = bS[h * 64 + e];
        #pragma unroll
        for (int r = 0; r < NPB; r++) {
            float v = acc[r] + bb;
            float s = v * v;
            for (int o = 32; o > 0; o >>= 1) s += __shfl_xor(s, o, 64);
            float nrm = sqrtf(s);
            wit[(rowbase + r) * 320 + 64 + e] = bf16bits(v / (nrm + EPSf));
        }
    }
    // ---- Hyperbolic ----
    {
        float acc[NPB];
        #pragma unroll
        for (int r = 0; r < NPB; r++) acc[r] = 0.f;
        const float* Wp = WH + (size_t)h * 64 * 64 + e;
        for (int d = 0; d < 64; d++) {
            float w = Wp[(size_t)d * 64];
            #pragma unroll
            for (int r = 0; r < NPB; r++) acc[r] = fmaf(xs[r][d], w, acc[r]);
        }
        float bb = bH[h * 64 + e];
        #pragma unroll
        for (int r = 0; r < NPB; r++) {
            float u = acc[r] + bb;
            float s = u * u;
            for (int o = 32; o > 0; o >>= 1) s += __shfl_xor(s, o, 64);
            float un = sqrtf(s);
            float sc = tanhf(un) / (un + EPSf);
            float w = sc * u;
            float wf = bf16rt(w);
            wit[(rowbase + r) * 320 + 128 + e] = bf16bits(w);
            float s2 = wf * wf;
            for (int o = 32; o > 0; o >>= 1) s2 += __shfl_xor(s2, o, 64);
            if (e == 0) {
                sqo[(rowbase + r) * 4 + 1] = s2;
                sqo[(rowbase + r) * 4 + 2] = 1.f - fminf(fmaxf(s2, 0.f), 1.f - 1e-5f);
            }
        }
    }
    // ---- RFF ----
    {
        float sF[NPB];
        #pragma unroll
        for (int r = 0; r < NPB; r++) sF[r] = 0.f;
        #pragma unroll
        for (int half = 0; half < 2; half++) {
            int col = e + 64 * half;
            float acc[NPB];
            #pragma unroll
            for (int r = 0; r < NPB; r++) acc[r] = 0.f;
            const float* Wp = Wrff + (size_t)h * 64 * 128 + col;
            for (int d = 0; d < 64; d++) {
                float w = Wp[(size_t)d * 128];
                #pragma unroll
                for (int r = 0; r < NPB; r++) acc[r] = fmaf(xs[r][d], w, acc[r]);
            }
            float bb = brff[h * 128 + col];
            #pragma unroll
            for (int r = 0; r < NPB; r++) {
                float zv = 0.125f * cosf(acc[r] + bb);
                float zf = bf16rt(zv);
                wit[(rowbase + r) * 320 + 192 + col] = bf16bits(zv);
                sF[r] += zf * zf;
            }
        }
        #pragma unroll
        for (int r = 0; r < NPB; r++) {
            float s = sF[r];
            for (int o = 32; o > 0; o >>= 1) s += __shfl_xor(s, o, 64);
            if (e == 0) sqo[(rowbase + r) * 4 + 3] = s;
        }
    }
}

// ---------------- convert f32 -> bf16 ----------------
__global__ void cvt_kernel(const float* __restrict__ src, unsigned short* __restrict__ dst, int n)
{
    int i = (blockIdx.x * blockDim.x + threadIdx.x) * 4;
    if (i < n) {
        float4 v = *(const float4*)(src + i);
        ushort4 o;
        o.x = bf16bits(v.x); o.y = bf16bits(v.y); o.z = bf16bits(v.z); o.w = bf16bits(v.w);
        *(ushort4*)(dst + i) = o;
    }
}

// ---------------- bf16 MFMA GEMM: C[M x 1024] = A[M x 1024] * W[1024 x 1024]^T + bias ----------------
// MODE 0: write f32 row-major to outF.  MODE 1: write bf16 to vt[bh][d][n] layout.
template<int MODE>
__global__ __launch_bounds__(256) void gemm_bf16_kernel(
    const unsigned short* __restrict__ A, const unsigned short* __restrict__ Bw,
    const float* __restrict__ bias, float* __restrict__ outF, unsigned short* __restrict__ outV)
{
    __shared__ __align__(16) char sm[24576];   // 2 x (At 8192 + Bt 4096)
    int tid = threadIdx.x, lane = tid & 63, w = tid >> 6;
    int wm = w >> 1, wn = w & 1;
    int i0 = blockIdx.y * 128, j0 = blockIdx.x * 64;
    const char* Ab = (const char*)A;
    const char* Bb = (const char*)Bw;

    f4v acc[4][2];
    #pragma unroll
    for (int i = 0; i < 4; i++) { acc[i][0] = (f4v){}; acc[i][1] = (f4v){}; }

    auto stage = [&](int kt, int buf) {
        char* atb = sm + buf * 12288;
        char* btb = atb + 8192;
        #pragma unroll
        for (int j = 0; j < 2; j++) {
            int id = w * 128 + j * 64 + lane;
            int row = id >> 2, u = id & 3;
            gl_lds16(Ab + (size_t)(i0 + row) * 2048 + kt * 64 + u * 16,
                     atb + w * 2048 + j * 1024);
        }
        {
            int id = w * 64 + lane;
            int row = id >> 2, u = id & 3;
            gl_lds16(Bb + (size_t)(j0 + row) * 2048 + kt * 64 + u * 16,
                     btb + w * 1024);
        }
    };

    stage(0, 0);
    __syncthreads();
    for (int kt = 0; kt < 32; kt++) {
        int buf = kt & 1;
        if (kt < 31) stage(kt + 1, buf ^ 1);
        const char* atb = sm + buf * 12288;
        const char* btb = atb + 8192;
        s8v af[4], bf[2];
        #pragma unroll
        for (int fi = 0; fi < 4; fi++)
            af[fi] = *(const s8v*)(atb + (wm * 64 + fi * 16 + (lane & 15)) * 64 + (lane >> 4) * 16);
        #pragma unroll
        for (int fj = 0; fj < 2; fj++)
            bf[fj] = *(const s8v*)(btb + (wn * 32 + fj * 16 + (lane & 15)) * 64 + (lane >> 4) * 16);
        #pragma unroll
        for (int fi = 0; fi < 4; fi++)
            #pragma unroll
            for (int fj = 0; fj < 2; fj++)
                acc[fi][fj] = MFMA16x16(af[fi], bf[fj], acc[fi][fj]);
        __syncthreads();
    }

    #pragma unroll
    for (int fi = 0; fi < 4; fi++)
        #pragma unroll
        for (int fj = 0; fj < 2; fj++)
            #pragma unroll
            for (int r = 0; r < 4; r++) {
                int grow = i0 + wm * 64 + fi * 16 + (lane >> 4) * 4 + r;
                int gcol = j0 + wn * 32 + fj * 16 + (lane & 15);
                float v = acc[fi][fj][r] + bias[gcol];
                if (MODE == 0) {
                    outF[(size_t)grow * 1024 + gcol] = v;
                } else {
                    int bb = grow >> 10, n = grow & 1023;
                    int hh = gcol >> 6, dd = gcol & 63;
                    outV[((size_t)(bb * 16 + hh) * 64 + dd) * 1024 + n] = bf16bits(v);
                }
            }
}

// ---------------- Kernel 3: MFMA distances + online softmax + MFMA PV ----------------
// 1024 blocks (XCD-swizzled), 4 waves per block = 4-way k-parity over one 32-q tile.
// No per-iter LDS staging or barriers: K/V fragments read direct from global (L2-resident),
// sq/mask preloaded once into LDS (broadcast reads only).
// LDS map: [0:16384) sqAll / merge O-slots(2x8192); [16384:20480) maskAll / merge m,l; [20480:21504) scl (256B/wave)
__global__ __launch_bounds__(256, 4) void attn_kernel(
    const unsigned short* __restrict__ wit, const float* __restrict__ sqb,
    const unsigned short* __restrict__ vt, const int* __restrict__ mask,
    const float* __restrict__ al_, const float* __restrict__ be_,
    const float* __restrict__ ga_, const float* __restrict__ de_,
    const float* __restrict__ tp_,
    __hip_bfloat16* __restrict__ aout)
{
    __shared__ __align__(16) char sm[21504];
    int tid = threadIdx.x, lane = tid & 63;
    int par = tid >> 6;                       // 0..3: k-parity
    int h8 = lane >> 5, l31 = lane & 31, h4 = h8 * 4;

    // XCD-aware decode: 128 consecutive slots per XCD; 4 bh-groups x 32 q-tiles each
    int bid = blockIdx.x;
    int xcd = bid & 7, slot = bid >> 3;       // slot 0..127
    int bh = (xcd << 2) | (slot >> 5);        // 0..31
    int qt = slot & 31;
    int bz = bh >> 4, hh = bh & 15;
    int q0 = qt * 32;

    const char* witb = (const char*)wit + (size_t)bh * Nd * 640;
    const char* vtb = (const char*)vt + (size_t)bh * 64 * 1024 * 2;

    float* sqAll = (float*)sm;                       // [1024][4]
    const int* mkAll = (const int*)(sm + 16384);     // [1024]
    float* sclw = (float*)(sm + 20480 + par * 256);  // 32 floats broadcast per wave

    // ---- one-time stage of sq (16KB) and mask (4KB) ----
    #pragma unroll
    for (int j = 0; j < 4; j++) {
        int blk = par * 4 + j;                       // 0..15 KB-chunks
        gl_lds16((const char*)sqb + (size_t)bh * 16384 + blk * 1024 + lane * 16,
                 sm + blk * 1024);
    }
    gl_lds16((const char*)(mask + (size_t)bz * Nd) + par * 1024 + lane * 16,
             sm + 16384 + par * 1024);

    // ---- per-lane Q row: fragments + row scalars ----
    s8v qf[20];
    {
        const char* qrowp = witb + (size_t)(q0 + l31) * 640;
        #pragma unroll
        for (int c = 0; c < 20; c++)
            qf[c] = *(const s8v*)(qrowp + c * 32 + h8 * 16);
    }
    f4v sqq = *(const f4v*)(sqb + (size_t)(bh * Nd + q0 + l31) * 4);
    const float LOG2E = 1.4426950408889634f;
    const float LN2 = 0.6931471805599453f;
    float itmp2 = LOG2E / tp_[hh];
    float al2 = -al_[hh] * itmp2;
    float be2 = -be_[hh] * itmp2;
    float de2 = -de_[hh] * itmp2;
    float gl2 = -ga_[hh] * itmp2 * LN2;       // dH computed as log2 -> fold ln2
    float sqqxE = sqq.x + EPSf, sqqwE = sqq.w + EPSf;
    float sqqy = sqq.y, sqqz = sqq.z;

    const char* kptr = witb + (size_t)l31 * 640 + h8 * 16;

    float m_run = -INFINITY, l_run = 0.f;
    f16v o0 = {}, o1 = {};

    __syncthreads();   // sq/mask staged

    for (int it = 0; it < 8; it++) {
        int k0 = (it * 4 + par) * 32;
        const char* kp = kptr + (size_t)k0 * 640;

        // ---- grams: D = K . Q^T  (row=k, col=q=lane&31), A-frags direct from global ----
        __builtin_amdgcn_s_setprio(1);
        f16v aE = {}, aS = {}, aH = {}, aF = {};
        #pragma unroll
        for (int c = 0; c < 20; c++) {
            s8v a = *(const s8v*)(kp + c * 32);
            if (c < 4)       aE = MFMA32x32(a, qf[c], aE);
            else if (c < 8)  aS = MFMA32x32(a, qf[c], aS);
            else if (c < 12) aH = MFMA32x32(a, qf[c], aH);
            else             aF = MFMA32x32(a, qf[c], aF);
        }
        __builtin_amdgcn_s_setprio(0);

        // ---- distances -> logits (log2 domain) ----
        float p[16];
        #pragma unroll
        for (int r = 0; r < 16; r++) {
            int kr = (r & 3) + 8 * (r >> 2) + h4;
            const float4 sk = *(const float4*)(sqAll + (size_t)(k0 + kr) * 4);
            float sE = fmaxf(fmaf(-2.f, aE[r], sqqxE + sk.x), EPSf);
            float dE = __builtin_amdgcn_sqrtf(sE);
            float cv = aS[r];
            float ax = fminf(fabsf(cv), 1.f - EPSf);
            float sq1 = __builtin_amdgcn_sqrtf(1.f - ax);
            float pa = sq1 * fmaf(ax, fmaf(ax, fmaf(ax, -0.0187293f, 0.0742610f), -0.2121144f), 1.5707288f);
            float dS = (cv < 0.f) ? (3.14159265f - pa) : pa;
            float d2 = fmaxf(fmaf(-2.f, aH[r], sqqy + sk.y), 0.f);
            float den = fmaf(sqqz, sk.z, EPSf);
            float arx = fmaxf(fmaf(d2 + d2, __builtin_amdgcn_rcpf(den), 1.f), 1.f + EPSf);
            float sh = __builtin_amdgcn_sqrtf(fmaf(arx, arx, -1.f));
            float lH = log2f(arx + sh);
            float sF = fmaxf(fmaf(-2.f, aF[r], sqqwE + sk.w), EPSf);
            float dF = __builtin_amdgcn_sqrtf(sF);
            float lg = fmaf(al2, dE, fmaf(be2, dS, fmaf(de2, dF, gl2 * lH)));
            p[r] = (mkAll[k0 + kr] > 0) ? lg : -1e9f;
        }

        // ---- online softmax with defer-max (THR = 8 in log2 units -> p <= 256) ----
        float mt = p[0];
        #pragma unroll
        for (int r = 1; r < 16; r++) mt = fmaxf(mt, p[r]);
        mt = fmaxf(mt, __shfl_xor(mt, 32, 64));
        if (!__all(mt <= m_run + 8.f)) {
            float mnew = fmaxf(m_run, mt);
            float sc = exp2f(m_run - mnew);
            l_run *= sc;
            m_run = mnew;
            if (lane < 32) sclw[l31] = sc;
            #pragma unroll
            for (int r = 0; r < 16; r++) {
                float s = sclw[(r & 3) + 8 * (r >> 2) + h4];
                o0[r] *= s; o1[r] *= s;
            }
        }
        float ps = 0.f;
        #pragma unroll
        for (int r = 0; r < 16; r++) { p[r] = exp2f(p[r] - m_run); ps += p[r]; }
        ps += __shfl_xor(ps, 32, 64);
        l_run += ps;

        // ---- P relayout: f32 (D-layout) -> bf16 A-frags via cvt_pk + permlane32_swap ----
        unsigned int w0, w1, w2, w3, y0, y1, y2, y3;
        asm("v_cvt_pk_bf16_f32 %0, %1, %2" : "=v"(w0) : "v"(p[0]), "v"(p[1]));
        asm("v_cvt_pk_bf16_f32 %0, %1, %2" : "=v"(w1) : "v"(p[2]), "v"(p[3]));
        asm("v_cvt_pk_bf16_f32 %0, %1, %2" : "=v"(w2) : "v"(p[4]), "v"(p[5]));
        asm("v_cvt_pk_bf16_f32 %0, %1, %2" : "=v"(w3) : "v"(p[6]), "v"(p[7]));
        asm("v_cvt_pk_bf16_f32 %0, %1, %2" : "=v"(y0) : "v"(p[8]), "v"(p[9]));
        asm("v_cvt_pk_bf16_f32 %0, %1, %2" : "=v"(y1) : "v"(p[10]), "v"(p[11]));
        asm("v_cvt_pk_bf16_f32 %0, %1, %2" : "=v"(y2) : "v"(p[12]), "v"(p[13]));
        asm("v_cvt_pk_bf16_f32 %0, %1, %2" : "=v"(y3) : "v"(p[14]), "v"(p[15]));
        asm volatile("v_permlane32_swap_b32 %0, %1" : "+v"(w0), "+v"(w2));
        asm volatile("v_permlane32_swap_b32 %0, %1" : "+v"(w1), "+v"(w3));
        asm volatile("v_permlane32_swap_b32 %0, %1" : "+v"(y0), "+v"(y2));
        asm volatile("v_permlane32_swap_b32 %0, %1" : "+v"(y1), "+v"(y3));
        int4 t1; t1.x = (int)w0; t1.y = (int)w1; t1.z = (int)w2; t1.w = (int)w3;
        int4 t2; t2.x = (int)y0; t2.y = (int)y1; t2.z = (int)y2; t2.w = (int)y3;
        s8v A1 = *(s8v*)&t1;
        s8v A2 = *(s8v*)&t2;

        // ---- PV: O += P . V   (V fragments direct from global, vt is [bh][d][n]) ----
        const char* vb0 = vtb + ((size_t)l31 * 1024 + k0 + h8 * 8) * 2;
        s8v b00 = *(const s8v*)(vb0);
        s8v b10 = *(const s8v*)(vb0 + 32);
        s8v b01 = *(const s8v*)(vb0 + 32 * 2048);
        s8v b11 = *(const s8v*)(vb0 + 32 * 2048 + 32);
        __builtin_amdgcn_s_setprio(1);
        o0 = MFMA32x32(A1, b00, o0);
        o0 = MFMA32x32(A2, b10, o0);
        o1 = MFMA32x32(A1, b01, o1);
        o1 = MFMA32x32(A2, b11, o1);
        __builtin_amdgcn_s_setprio(0);
    }

    // ---- merge 4 parity partials (tree: {2,3}->{0,1}, then 1->0) ----
    float* slotO0 = (float*)sm;                 // 32q x 64d
    float* slotO1 = (float*)(sm + 8192);
    float* slotM0 = (float*)(sm + 16384);       // m[32], l[32]
    float* slotM1 = (float*)(sm + 16384 + 512);

    __syncthreads();
    if (par >= 2) {
        float* so = (par == 2) ? slotO0 : slotO1;
        float* sM = (par == 2) ? slotM0 : slotM1;
        #pragma unroll
        for (int r = 0; r < 16; r++) {
            int qr = (r & 3) + 8 * (r >> 2) + h4;
            so[qr * 64 + l31] = o0[r];
            so[qr * 64 + 32 + l31] = o1[r];
        }
        if (lane < 32) { sM[lane] = m_run; sM[32 + lane] = l_run; }
    }
    __syncthreads();
    if (par < 2) {
        float* so = (par == 0) ? slotO0 : slotO1;
        float* sM = (par == 0) ? slotM0 : slotM1;
        float m2 = sM[l31], l2 = sM[32 + l31];
        float M = fmaxf(m_run, m2);
        float s1 = exp2f(m_run - M), s2 = exp2f(m2 - M);
        l_run = l_run * s1 + l2 * s2;
        m_run = M;
        if (lane < 32) { sclw[l31] = s1; }
        float* scl2 = sclw + 32;
        if (lane < 32) { scl2[l31] = s2; }
        #pragma unroll
        for (int r = 0; r < 16; r++) {
            int qr = (r & 3) + 8 * (r >> 2) + h4;
            float a = sclw[qr], b = scl2[qr];
            o0[r] = o0[r] * a + so[qr * 64 + l31] * b;
            o1[r] = o1[r] * a + so[qr * 64 + 32 + l31] * b;
        }
    }
    __syncthreads();
    if (par == 1) {
        #pragma unroll
        for (int r = 0; r < 16; r++) {
            int qr = (r & 3) + 8 * (r >> 2) + h4;
            slotO0[qr * 64 + l31] = o0[r];
            slotO0[qr * 64 + 32 + l31] = o1[r];
        }
        if (lane < 32) { slotM0[lane] = m_run; slotM0[32 + lane] = l_run; }
    }
    __syncthreads();
    if (par == 0) {
        float m2 = slotM0[l31], l2 = slotM0[32 + l31];
        float M = fmaxf(m_run, m2);
        float s1 = exp2f(m_run - M), s2 = exp2f(m2 - M);
        float lt = l_run * s1 + l2 * s2;
        float inv = 1.f / lt;
        if (lane < 32) { sclw[l31] = s1 * inv; sclw[32 + l31] = s2 * inv; }
        #pragma unroll
        for (int r = 0; r < 16; r++) {
            int qr = (r & 3) + 8 * (r >> 2) + h4;
            float a = sclw[qr], b = sclw[32 + qr];
            float r0 = o0[r] * a + slotO0[qr * 64 + l31] * b;
            float r1 = o1[r] * a + slotO0[qr * 64 + 32 + l31] * b;
            size_t row = (size_t)bz * Nd + q0 + qr;
            aout[row * Dd + hh * 64 + l31] = __float2bfloat16(r0);
            aout[row * Dd + hh * 64 + 32 + l31] = __float2bfloat16(r1);
        }
    }
}

extern "C" void kernel_launch(void* const* d_in, const int* in_sizes, int n_in,
                              void* d_out, int out_size, void* d_ws, size_t ws_size,
                              hipStream_t stream) {
    const float* x    = (const float*)d_in[0];
    const int*   mask = (const int*)d_in[1];
    const float* WE   = (const float*)d_in[2];
    const float* bE   = (const float*)d_in[3];
    const float* WS   = (const float*)d_in[4];
    const float* bS   = (const float*)d_in[5];
    const float* WH   = (const float*)d_in[6];
    const float* bH   = (const float*)d_in[7];
    const float* Wrff = (const float*)d_in[8];
    const float* brff = (const float*)d_in[9];
    const float* alpha = (const float*)d_in[10];
    const float* beta  = (const float*)d_in[11];
    const float* gamma_ = (const float*)d_in[12];
    const float* delta = (const float*)d_in[13];
    const float* temperature = (const float*)d_in[14];
    const float* Wv = (const float*)d_in[15];
    const float* bv = (const float*)d_in[16];
    const float* Wo = (const float*)d_in[17];
    const float* bo = (const float*)d_in[18];

    char* ws = (char*)d_ws;
    size_t R = (size_t)Bd * Hh * Nd;                       // 32768
    unsigned short* wit = (unsigned short*)ws;             // R*320*2   = 20971520
    float* sq  = (float*)(ws + 20971520);                  // R*4*4     = 524288
    unsigned short* xb  = (unsigned short*)(ws + 21495808);// 2M*2      = 4194304
    unsigned short* wvb = (unsigned short*)(ws + 25690112);// 1M*2      = 2097152
    unsigned short* wob = (unsigned short*)(ws + 27787264);// 1M*2      = 2097152
    unsigned short* vt  = (unsigned short*)(ws + 29884416);// 2M*2      = 4194304
    __hip_bfloat16* aout = (__hip_bfloat16*)(ws + 34078720); // 2M*2    = 4194304

    witness_kernel<<<dim3(Bd * Hh * (Nd / NPB)), 64, 0, stream>>>(
        x, WE, bE, WS, bS, WH, bH, Wrff, brff, wit, sq, xb);

    cvt_kernel<<<dim3(1024), 256, 0, stream>>>(Wv, wvb, 1 << 20);
    cvt_kernel<<<dim3(1024), 256, 0, stream>>>(Wo, wob, 1 << 20);

    gemm_bf16_kernel<1><<<dim3(16, 16), 256, 0, stream>>>(xb, wvb, bv, nullptr, vt);

    attn_kernel<<<dim3(1024), 256, 0, stream>>>(
        wit, sq, vt, mask, alpha, beta, gamma_, delta, temperature, aout);

    gemm_bf16_kernel<0><<<dim3(16, 16), 256, 0, stream>>>(
        (const unsigned short*)aout, wob, bo, (float*)d_out, nullptr);
}

// Round 4
// 175.308 us; speedup vs baseline: 1.7997x; 1.7997x over previous
//
#include <hip/hip_runtime.h>
#include <hip/hip_bf16.h>
#include <math.h>
#include <stdint.h>

#define Bd 2
#define Nd 1024
#define Dd 1024
#define Hh 16
#define EPSf 1e-6f
#define NPB 8

typedef short s8v __attribute__((ext_vector_type(8)));
typedef float f16v __attribute__((ext_vector_type(16)));
typedef float f4v __attribute__((ext_vector_type(4)));

#define MFMA32x32(A,B,C) __builtin_amdgcn_mfma_f32_32x32x16_bf16(A,B,C,0,0,0)
#define MFMA16x16(A,B,C) __builtin_amdgcn_mfma_f32_16x16x32_bf16(A,B,C,0,0,0)

__device__ __forceinline__ void gl_lds16(const void* g, void* l) {
    __builtin_amdgcn_global_load_lds((const __attribute__((address_space(1))) unsigned int*)g,
                                     (__attribute__((address_space(3))) unsigned int*)l, 16, 0, 0);
}

__device__ __forceinline__ unsigned short bf16bits(float v) {
    __hip_bfloat16 h = __float2bfloat16(v);
    return *(unsigned short*)&h;
}
__device__ __forceinline__ float bf16rt(float v) {   // round-trip through bf16
    __hip_bfloat16 h = __float2bfloat16(v);
    return __bfloat162float(h);
}

// fragment-major witness store:
// wit2[bh][kblk=n>>5][c=f>>4][( (n&31)*2 + ((f>>3)&1) )*8 + (f&7)]  (ushort units; 10240/ kblk, 327680/bh)
__device__ __forceinline__ void wit_store(unsigned short* wit, size_t bh, int n, int f, float v) {
    size_t idx = bh * 327680 + (size_t)(n >> 5) * 10240 + (size_t)(f >> 4) * 512
               + (size_t)(((n & 31) * 2 + ((f >> 3) & 1)) * 8 + (f & 7));
    wit[idx] = bf16bits(v);
}

// ---------------- Kernel 1: witness projections -> fragment-major bf16 witness rows ----------------
__global__ void witness_kernel(const float* __restrict__ x,
    const float* __restrict__ WE, const float* __restrict__ bE,
    const float* __restrict__ WS, const float* __restrict__ bS,
    const float* __restrict__ WH, const float* __restrict__ bH,
    const float* __restrict__ Wrff, const float* __restrict__ brff,
    unsigned short* __restrict__ wit, float* __restrict__ sqo,
    unsigned short* __restrict__ xb)
{
    const int e = threadIdx.x;           // 0..63
    int idx = blockIdx.x;
    const int NC = Nd / NPB;             // 128
    int nc = idx % NC;
    int h = (idx / NC) % Hh;
    int b = idx / (NC * Hh);
    int n0 = nc * NPB;
    size_t bh = (size_t)b * Hh + h;

    __shared__ float xs[NPB][64];
    #pragma unroll
    for (int r = 0; r < NPB; r++) {
        float xv = x[((size_t)b * Nd + n0 + r) * Dd + h * 64 + e];
        xs[r][e] = xv;
        xb[((size_t)b * Nd + n0 + r) * Dd + h * 64 + e] = bf16bits(xv);
    }
    __syncthreads();

    size_t rowbase = (bh * Nd + n0);

    // ---- Euclidean (f = e) ----
    {
        float acc[NPB];
        #pragma unroll
        for (int r = 0; r < NPB; r++) acc[r] = 0.f;
        const float* Wp = WE + (size_t)h * 64 * 64 + e;
        for (int d = 0; d < 64; d++) {
            float w = Wp[(size_t)d * 64];
            #pragma unroll
            for (int r = 0; r < NPB; r++) acc[r] = fmaf(xs[r][d], w, acc[r]);
        }
        float bb = bE[h * 64 + e];
        #pragma unroll
        for (int r = 0; r < NPB; r++) {
            float v = acc[r] + bb;
            float vf = bf16rt(v);
            wit_store(wit, bh, n0 + r, e, v);
            float s = vf * vf;
            for (int o = 32; o > 0; o >>= 1) s += __shfl_xor(s, o, 64);
            if (e == 0) sqo[(rowbase + r) * 4 + 0] = s;
        }
    }
    // ---- Spherical (f = 64+e) ----
    {
        float acc[NPB];
        #pragma unroll
        for (int r = 0; r < NPB; r++) acc[r] = 0.f;
        const float* Wp = WS + (size_t)h * 64 * 64 + e;
        for (int d = 0; d < 64; d++) {
            float w = Wp[(size_t)d * 64];
            #pragma unroll
            for (int r = 0; r < NPB; r++) acc[r] = fmaf(xs[r][d], w, acc[r]);
        }
        float bb = bS[h * 64 + e];
        #pragma unroll
        for (int r = 0; r < NPB; r++) {
            float v = acc[r] + bb;
            float s = v * v;
            for (int o = 32; o > 0; o >>= 1) s += __shfl_xor(s, o, 64);
            float nrm = sqrtf(s);
            wit_store(wit, bh, n0 + r, 64 + e, v / (nrm + EPSf));
        }
    }
    // ---- Hyperbolic (f = 128+e) ----
    {
        float acc[NPB];
        #pragma unroll
        for (int r = 0; r < NPB; r++) acc[r] = 0.f;
        const float* Wp = WH + (size_t)h * 64 * 64 + e;
        for (int d = 0; d < 64; d++) {
            float w = Wp[(size_t)d * 64];
            #pragma unroll
            for (int r = 0; r < NPB; r++) acc[r] = fmaf(xs[r][d], w, acc[r]);
        }
        float bb = bH[h * 64 + e];
        #pragma unroll
        for (int r = 0; r < NPB; r++) {
            float u = acc[r] + bb;
            float s = u * u;
            for (int o = 32; o > 0; o >>= 1) s += __shfl_xor(s, o, 64);
            float un = sqrtf(s);
            float sc = tanhf(un) / (un + EPSf);
            float w = sc * u;
            float wf = bf16rt(w);
            wit_store(wit, bh, n0 + r, 128 + e, w);
            float s2 = wf * wf;
            for (int o = 32; o > 0; o >>= 1) s2 += __shfl_xor(s2, o, 64);
            if (e == 0) {
                sqo[(rowbase + r) * 4 + 1] = s2;
                sqo[(rowbase + r) * 4 + 2] = 1.f - fminf(fmaxf(s2, 0.f), 1.f - 1e-5f);
            }
        }
    }
    // ---- RFF (f = 192+col) ----
    {
        float sF[NPB];
        #pragma unroll
        for (int r = 0; r < NPB; r++) sF[r] = 0.f;
        #pragma unroll
        for (int half = 0; half < 2; half++) {
            int col = e + 64 * half;
            float acc[NPB];
            #pragma unroll
            for (int r = 0; r < NPB; r++) acc[r] = 0.f;
            const float* Wp = Wrff + (size_t)h * 64 * 128 + col;
            for (int d = 0; d < 64; d++) {
                float w = Wp[(size_t)d * 128];
                #pragma unroll
                for (int r = 0; r < NPB; r++) acc[r] = fmaf(xs[r][d], w, acc[r]);
            }
            float bb = brff[h * 128 + col];
            #pragma unroll
            for (int r = 0; r < NPB; r++) {
                float zv = 0.125f * cosf(acc[r] + bb);
                float zf = bf16rt(zv);
                wit_store(wit, bh, n0 + r, 192 + col, zv);
                sF[r] += zf * zf;
            }
        }
        #pragma unroll
        for (int r = 0; r < NPB; r++) {
            float s = sF[r];
            for (int o = 32; o > 0; o >>= 1) s += __shfl_xor(s, o, 64);
            if (e == 0) sqo[(rowbase + r) * 4 + 3] = s;
        }
    }
}

// ---------------- convert f32 -> bf16 ----------------
__global__ void cvt_kernel(const float* __restrict__ src, unsigned short* __restrict__ dst, int n)
{
    int i = (blockIdx.x * blockDim.x + threadIdx.x) * 4;
    if (i < n) {
        float4 v = *(const float4*)(src + i);
        ushort4 o;
        o.x = bf16bits(v.x); o.y = bf16bits(v.y); o.z = bf16bits(v.z); o.w = bf16bits(v.w);
        *(ushort4*)(dst + i) = o;
    }
}

// ---------------- bf16 MFMA GEMM: C[M x 1024] = A[M x 1024] * W[1024 x 1024]^T + bias ----------------
// MODE 0: write f32 row-major to outF.  MODE 1: write bf16 to fragment-major vt2 layout.
template<int MODE>
__global__ __launch_bounds__(256) void gemm_bf16_kernel(
    const unsigned short* __restrict__ A, const unsigned short* __restrict__ Bw,
    const float* __restrict__ bias, float* __restrict__ outF, unsigned short* __restrict__ outV)
{
    __shared__ __align__(16) char sm[24576];   // 2 x (At 8192 + Bt 4096)
    int tid = threadIdx.x, lane = tid & 63, w = tid >> 6;
    int wm = w >> 1, wn = w & 1;
    int i0 = blockIdx.y * 128, j0 = blockIdx.x * 64;
    const char* Ab = (const char*)A;
    const char* Bb = (const char*)Bw;

    f4v acc[4][2];
    #pragma unroll
    for (int i = 0; i < 4; i++) { acc[i][0] = (f4v){}; acc[i][1] = (f4v){}; }

    auto stage = [&](int kt, int buf) {
        char* atb = sm + buf * 12288;
        char* btb = atb + 8192;
        #pragma unroll
        for (int j = 0; j < 2; j++) {
            int id = w * 128 + j * 64 + lane;
            int row = id >> 2, u = id & 3;
            gl_lds16(Ab + (size_t)(i0 + row) * 2048 + kt * 64 + u * 16,
                     atb + w * 2048 + j * 1024);
        }
        {
            int id = w * 64 + lane;
            int row = id >> 2, u = id & 3;
            gl_lds16(Bb + (size_t)(j0 + row) * 2048 + kt * 64 + u * 16,
                     btb + w * 1024);
        }
    };

    stage(0, 0);
    __syncthreads();
    for (int kt = 0; kt < 32; kt++) {
        int buf = kt & 1;
        if (kt < 31) stage(kt + 1, buf ^ 1);
        const char* atb = sm + buf * 12288;
        const char* btb = atb + 8192;
        s8v af[4], bf[2];
        #pragma unroll
        for (int fi = 0; fi < 4; fi++)
            af[fi] = *(const s8v*)(atb + (wm * 64 + fi * 16 + (lane & 15)) * 64 + (lane >> 4) * 16);
        #pragma unroll
        for (int fj = 0; fj < 2; fj++)
            bf[fj] = *(const s8v*)(btb + (wn * 32 + fj * 16 + (lane & 15)) * 64 + (lane >> 4) * 16);
        #pragma unroll
        for (int fi = 0; fi < 4; fi++)
            #pragma unroll
            for (int fj = 0; fj < 2; fj++)
                acc[fi][fj] = MFMA16x16(af[fi], bf[fj], acc[fi][fj]);
        __syncthreads();
    }

    #pragma unroll
    for (int fi = 0; fi < 4; fi++)
        #pragma unroll
        for (int fj = 0; fj < 2; fj++)
            #pragma unroll
            for (int r = 0; r < 4; r++) {
                int grow = i0 + wm * 64 + fi * 16 + (lane >> 4) * 4 + r;
                int gcol = j0 + wn * 32 + fj * 16 + (lane & 15);
                float v = acc[fi][fj][r] + bias[gcol];
                if (MODE == 0) {
                    outF[(size_t)grow * 1024 + gcol] = v;
                } else {
                    int bb = grow >> 10, n = grow & 1023;
                    int hh = gcol >> 6, dd = gcol & 63;
                    int bh2 = bb * 16 + hh, kblk = n >> 5, kk = n & 31;
                    int kh = kk >> 4, h8v = (kk >> 3) & 1, jj = kk & 7;
                    int dh = dd >> 5, l31v = dd & 31;
                    outV[(size_t)bh2 * 65536 + kblk * 2048 + (kh * 2 + dh) * 512
                         + (l31v * 2 + h8v) * 8 + jj] = bf16bits(v);
                }
            }
}

// ---------------- Kernel 3: MFMA distances + online softmax + MFMA PV ----------------
// 1024 blocks (XCD-swizzled), 4 waves per block = 4-way k-parity over one 32-q tile.
// K/V fragment-major in global (coalesced 1KB wave reads, L2-resident); Q tile in LDS;
// sq/mask in LDS; no barriers in main loop.
// LDS map: [0:16384) sqAll (merge: O-slots 2x8K); [16384:20480) mkAll (merge: m,l); [20480:40960) Q; [40960:41984) scl
__global__ __launch_bounds__(256, 3) void attn_kernel(
    const unsigned short* __restrict__ wit, const float* __restrict__ sqb,
    const unsigned short* __restrict__ vt, const int* __restrict__ mask,
    const float* __restrict__ al_, const float* __restrict__ be_,
    const float* __restrict__ ga_, const float* __restrict__ de_,
    const float* __restrict__ tp_,
    __hip_bfloat16* __restrict__ aout)
{
    __shared__ __align__(16) char sm[41984];
    int tid = threadIdx.x, lane = tid & 63;
    int par = tid >> 6;                       // 0..3: k-parity
    int h8 = lane >> 5, l31 = lane & 31, h4 = h8 * 4;

    // XCD-aware decode: 128 consecutive slots per XCD; 4 bh-groups x 32 q-tiles each
    int bid = blockIdx.x;
    int xcd = bid & 7, slot = bid >> 3;       // slot 0..127
    int bh = (xcd << 2) | (slot >> 5);        // 0..31
    int qt = slot & 31;
    int bz = bh >> 4, hh = bh & 15;
    int q0 = qt * 32;

    const char* witb = (const char*)wit + (size_t)bh * 655360;
    const char* vtb = (const char*)vt + (size_t)bh * 131072;

    float* sqAll = (float*)sm;                       // [1024][4]
    const int* mkAll = (const int*)(sm + 16384);     // [1024]
    char* qlds = sm + 20480;                         // 20KB Q tile (fragment-major)
    float* sclw = (float*)(sm + 40960 + par * 256);  // 32 floats broadcast per wave

    // ---- one-time stage: sq (16KB), mask (4KB), Q tile (20KB) ----
    #pragma unroll
    for (int j = 0; j < 4; j++) {
        int blk = par * 4 + j;                       // 16 chunks of 1KB
        gl_lds16((const char*)sqb + (size_t)bh * 16384 + blk * 1024 + lane * 16,
                 sm + blk * 1024);
    }
    gl_lds16((const char*)(mask + (size_t)bz * Nd) + par * 1024 + lane * 16,
             sm + 16384 + par * 1024);
    #pragma unroll
    for (int j = 0; j < 5; j++) {
        int ch = par * 5 + j;                        // 20 chunks of 1KB
        gl_lds16(witb + (size_t)qt * 20480 + ch * 1024 + lane * 16,
                 qlds + ch * 1024);
    }

    int laneoff = (l31 * 2 + h8) * 16;

    f4v sqq = *(const f4v*)(sqb + ((size_t)bh * Nd + q0 + l31) * 4);
    const float LOG2E = 1.4426950408889634f;
    const float LN2 = 0.6931471805599453f;
    float itmp2 = LOG2E / tp_[hh];
    float al2 = -al_[hh] * itmp2;
    float be2 = -be_[hh] * itmp2;
    float de2 = -de_[hh] * itmp2;
    float gl2 = -ga_[hh] * itmp2 * LN2;       // dH computed as log2 -> fold ln2
    float sqqxE = sqq.x + EPSf, sqqwE = sqq.w + EPSf;
    float sqqy = sqq.y, sqqz = sqq.z;

    float m_run = -INFINITY, l_run = 0.f;
    f16v o0 = {}, o1 = {};

    __syncthreads();   // staging complete

    for (int it = 0; it < 8; it++) {
        int kblk = it * 4 + par;
        int k0 = kblk * 32;
        const char* kp = witb + (size_t)kblk * 20480 + laneoff;

        // ---- grams: D = K . Q^T  (row=k, col=q=lane&31); K frags from global, Q frags from LDS ----
        __builtin_amdgcn_s_setprio(1);
        f16v aE = {}, aS = {}, aH = {}, aF = {};
        #pragma unroll
        for (int c = 0; c < 20; c++) {
            s8v a = *(const s8v*)(kp + c * 1024);
            s8v q = *(const s8v*)(qlds + c * 1024 + laneoff);
            if (c < 4)       aE = MFMA32x32(a, q, aE);
            else if (c < 8)  aS = MFMA32x32(a, q, aS);
            else if (c < 12) aH = MFMA32x32(a, q, aH);
            else             aF = MFMA32x32(a, q, aF);
        }
        __builtin_amdgcn_s_setprio(0);

        // ---- distances -> logits (log2 domain) ----
        float p[16];
        #pragma unroll
        for (int r = 0; r < 16; r++) {
            int kr = (r & 3) + 8 * (r >> 2) + h4;
            const float4 sk = *(const float4*)(sqAll + (size_t)(k0 + kr) * 4);
            float sE = fmaxf(fmaf(-2.f, aE[r], sqqxE + sk.x), EPSf);
            float dE = __builtin_amdgcn_sqrtf(sE);
            float cv = aS[r];
            float ax = fminf(fabsf(cv), 1.f - EPSf);
            float sq1 = __builtin_amdgcn_sqrtf(1.f - ax);
            float pa = sq1 * fmaf(ax, fmaf(ax, fmaf(ax, -0.0187293f, 0.0742610f), -0.2121144f), 1.5707288f);
            float dS = (cv < 0.f) ? (3.14159265f - pa) : pa;
            float d2 = fmaxf(fmaf(-2.f, aH[r], sqqy + sk.y), 0.f);
            float den = fmaf(sqqz, sk.z, EPSf);
            float arx = fmaxf(fmaf(d2 + d2, __builtin_amdgcn_rcpf(den), 1.f), 1.f + EPSf);
            float sh = __builtin_amdgcn_sqrtf(fmaf(arx, arx, -1.f));
            float lH = log2f(arx + sh);
            float sF = fmaxf(fmaf(-2.f, aF[r], sqqwE + sk.w), EPSf);
            float dF = __builtin_amdgcn_sqrtf(sF);
            float lg = fmaf(al2, dE, fmaf(be2, dS, fmaf(de2, dF, gl2 * lH)));
            p[r] = (mkAll[k0 + kr] > 0) ? lg : -1e9f;
        }

        // ---- online softmax with defer-max (THR = 8 in log2 units) ----
        float mt = p[0];
        #pragma unroll
        for (int r = 1; r < 16; r++) mt = fmaxf(mt, p[r]);
        mt = fmaxf(mt, __shfl_xor(mt, 32, 64));
        if (!__all(mt <= m_run + 8.f)) {
            float mnew = fmaxf(m_run, mt);
            float sc = exp2f(m_run - mnew);
            l_run *= sc;
            m_run = mnew;
            if (lane < 32) sclw[l31] = sc;
            #pragma unroll
            for (int r = 0; r < 16; r++) {
                float s = sclw[(r & 3) + 8 * (r >> 2) + h4];
                o0[r] *= s; o1[r] *= s;
            }
        }
        float ps = 0.f;
        #pragma unroll
        for (int r = 0; r < 16; r++) { p[r] = exp2f(p[r] - m_run); ps += p[r]; }
        ps += __shfl_xor(ps, 32, 64);
        l_run += ps;

        // ---- P relayout: f32 (D-layout) -> bf16 A-frags via cvt_pk + permlane32_swap ----
        unsigned int w0, w1, w2, w3, y0, y1, y2, y3;
        asm("v_cvt_pk_bf16_f32 %0, %1, %2" : "=v"(w0) : "v"(p[0]), "v"(p[1]));
        asm("v_cvt_pk_bf16_f32 %0, %1, %2" : "=v"(w1) : "v"(p[2]), "v"(p[3]));
        asm("v_cvt_pk_bf16_f32 %0, %1, %2" : "=v"(w2) : "v"(p[4]), "v"(p[5]));
        asm("v_cvt_pk_bf16_f32 %0, %1, %2" : "=v"(w3) : "v"(p[6]), "v"(p[7]));
        asm("v_cvt_pk_bf16_f32 %0, %1, %2" : "=v"(y0) : "v"(p[8]), "v"(p[9]));
        asm("v_cvt_pk_bf16_f32 %0, %1, %2" : "=v"(y1) : "v"(p[10]), "v"(p[11]));
        asm("v_cvt_pk_bf16_f32 %0, %1, %2" : "=v"(y2) : "v"(p[12]), "v"(p[13]));
        asm("v_cvt_pk_bf16_f32 %0, %1, %2" : "=v"(y3) : "v"(p[14]), "v"(p[15]));
        asm volatile("v_permlane32_swap_b32 %0, %1" : "+v"(w0), "+v"(w2));
        asm volatile("v_permlane32_swap_b32 %0, %1" : "+v"(w1), "+v"(w3));
        asm volatile("v_permlane32_swap_b32 %0, %1" : "+v"(y0), "+v"(y2));
        asm volatile("v_permlane32_swap_b32 %0, %1" : "+v"(y1), "+v"(y3));
        int4 t1; t1.x = (int)w0; t1.y = (int)w1; t1.z = (int)w2; t1.w = (int)w3;
        int4 t2; t2.x = (int)y0; t2.y = (int)y1; t2.z = (int)y2; t2.w = (int)y3;
        s8v A1 = *(s8v*)&t1;
        s8v A2 = *(s8v*)&t2;

        // ---- PV: O += P . V   (V frags from global, fragment-major, coalesced) ----
        const char* vp = vtb + (size_t)kblk * 4096 + laneoff;
        s8v b00 = *(const s8v*)(vp);             // k 0..15,  d 0..31
        s8v b01 = *(const s8v*)(vp + 1024);      // k 0..15,  d 32..63
        s8v b10 = *(const s8v*)(vp + 2048);      // k 16..31, d 0..31
        s8v b11 = *(const s8v*)(vp + 3072);      // k 16..31, d 32..63
        __builtin_amdgcn_s_setprio(1);
        o0 = MFMA32x32(A1, b00, o0);
        o0 = MFMA32x32(A2, b10, o0);
        o1 = MFMA32x32(A1, b01, o1);
        o1 = MFMA32x32(A2, b11, o1);
        __builtin_amdgcn_s_setprio(0);
    }

    // ---- merge 4 parity partials (tree: {2,3}->{0,1}, then 1->0) ----
    float* slotO0 = (float*)sm;                 // 32q x 64d
    float* slotO1 = (float*)(sm + 8192);
    float* slotM0 = (float*)(sm + 16384);       // m[32], l[32]
    float* slotM1 = (float*)(sm + 16896);

    __syncthreads();
    if (par >= 2) {
        float* so = (par == 2) ? slotO0 : slotO1;
        float* sM = (par == 2) ? slotM0 : slotM1;
        #pragma unroll
        for (int r = 0; r < 16; r++) {
            int qr = (r & 3) + 8 * (r >> 2) + h4;
            so[qr * 64 + l31] = o0[r];
            so[qr * 64 + 32 + l31] = o1[r];
        }
        if (lane < 32) { sM[lane] = m_run; sM[32 + lane] = l_run; }
    }
    __syncthreads();
    if (par < 2) {
        float* so = (par == 0) ? slotO0 : slotO1;
        float* sM = (par == 0) ? slotM0 : slotM1;
        float m2 = sM[l31], l2 = sM[32 + l31];
        float M = fmaxf(m_run, m2);
        float s1 = exp2f(m_run - M), s2 = exp2f(m2 - M);
        l_run = l_run * s1 + l2 * s2;
        m_run = M;
        if (lane < 32) { sclw[l31] = s1; }
        float* scl2 = sclw + 32;
        if (lane < 32) { scl2[l31] = s2; }
        #pragma unroll
        for (int r = 0; r < 16; r++) {
            int qr = (r & 3) + 8 * (r >> 2) + h4;
            float a = sclw[qr], b = scl2[qr];
            o0[r] = o0[r] * a + so[qr * 64 + l31] * b;
            o1[r] = o1[r] * a + so[qr * 64 + 32 + l31] * b;
        }
    }
    __syncthreads();
    if (par == 1) {
        #pragma unroll
        for (int r = 0; r < 16; r++) {
            int qr = (r & 3) + 8 * (r >> 2) + h4;
            slotO0[qr * 64 + l31] = o0[r];
            slotO0[qr * 64 + 32 + l31] = o1[r];
        }
        if (lane < 32) { slotM0[lane] = m_run; slotM0[32 + lane] = l_run; }
    }
    __syncthreads();
    if (par == 0) {
        float m2 = slotM0[l31], l2 = slotM0[32 + l31];
        float M = fmaxf(m_run, m2);
        float s1 = exp2f(m_run - M), s2 = exp2f(m2 - M);
        float lt = l_run * s1 + l2 * s2;
        float inv = 1.f / lt;
        if (lane < 32) { sclw[l31] = s1 * inv; sclw[32 + l31] = s2 * inv; }
        #pragma unroll
        for (int r = 0; r < 16; r++) {
            int qr = (r & 3) + 8 * (r >> 2) + h4;
            float a = sclw[qr], b = sclw[32 + qr];
            float r0 = o0[r] * a + slotO0[qr * 64 + l31] * b;
            float r1 = o1[r] * a + slotO0[qr * 64 + 32 + l31] * b;
            size_t row = (size_t)bz * Nd + q0 + qr;
            aout[row * Dd + hh * 64 + l31] = __float2bfloat16(r0);
            aout[row * Dd + hh * 64 + 32 + l31] = __float2bfloat16(r1);
        }
    }
}

extern "C" void kernel_launch(void* const* d_in, const int* in_sizes, int n_in,
                              void* d_out, int out_size, void* d_ws, size_t ws_size,
                              hipStream_t stream) {
    const float* x    = (const float*)d_in[0];
    const int*   mask = (const int*)d_in[1];
    const float* WE   = (const float*)d_in[2];
    const float* bE   = (const float*)d_in[3];
    const float* WS   = (const float*)d_in[4];
    const float* bS   = (const float*)d_in[5];
    const float* WH   = (const float*)d_in[6];
    const float* bH   = (const float*)d_in[7];
    const float* Wrff = (const float*)d_in[8];
    const float* brff = (const float*)d_in[9];
    const float* alpha = (const float*)d_in[10];
    const float* beta  = (const float*)d_in[11];
    const float* gamma_ = (const float*)d_in[12];
    const float* delta = (const float*)d_in[13];
    const float* temperature = (const float*)d_in[14];
    const float* Wv = (const float*)d_in[15];
    const float* bv = (const float*)d_in[16];
    const float* Wo = (const float*)d_in[17];
    const float* bo = (const float*)d_in[18];

    char* ws = (char*)d_ws;
    unsigned short* wit = (unsigned short*)ws;             // 32768*320*2 = 20971520
    float* sq  = (float*)(ws + 20971520);                  // 32768*4*4   = 524288
    unsigned short* xb  = (unsigned short*)(ws + 21495808);// 2M*2        = 4194304
    unsigned short* wvb = (unsigned short*)(ws + 25690112);// 1M*2        = 2097152
    unsigned short* wob = (unsigned short*)(ws + 27787264);// 1M*2        = 2097152
    unsigned short* vt  = (unsigned short*)(ws + 29884416);// 2M*2        = 4194304
    __hip_bfloat16* aout = (__hip_bfloat16*)(ws + 34078720); // 2M*2      = 4194304

    witness_kernel<<<dim3(Bd * Hh * (Nd / NPB)), 64, 0, stream>>>(
        x, WE, bE, WS, bS, WH, bH, Wrff, brff, wit, sq, xb);

    cvt_kernel<<<dim3(1024), 256, 0, stream>>>(Wv, wvb, 1 << 20);
    cvt_kernel<<<dim3(1024), 256, 0, stream>>>(Wo, wob, 1 << 20);

    gemm_bf16_kernel<1><<<dim3(16, 16), 256, 0, stream>>>(xb, wvb, bv, nullptr, vt);

    attn_kernel<<<dim3(1024), 256, 0, stream>>>(
        wit, sq, vt, mask, alpha, beta, gamma_, delta, temperature, aout);

    gemm_bf16_kernel<0><<<dim3(16, 16), 256, 0, stream>>>(
        (const unsigned short*)aout, wob, bo, (float*)d_out, nullptr);
}